// Round 4
// baseline (2476.237 us; speedup 1.0000x reference)
//
#include <hip/hip_runtime.h>
#include <hip/hip_bf16.h>
#include <math.h>
#include <cstdint>

typedef unsigned short u16;

#define B_   64
#define HH   28
#define WW   28
#define C_   384
#define NH_  6
#define HD   64
#define T_   784      // 28*28 queries
#define TK   169      // 13*13 keys

using frag_ab = __attribute__((ext_vector_type(8))) short;   // 8 x bf16
using frag_cd = __attribute__((ext_vector_type(4))) float;   // 4 x fp32

__device__ inline float b2f(u16 u) {
    union { unsigned int i; float f; } v; v.i = ((unsigned int)u) << 16; return v.f;
}
__device__ inline u16 f2b(float f) {
    union { unsigned int i; float f; } v; v.f = f;
    unsigned int i = v.i;
    i += 0x7fffu + ((i >> 16) & 1);   // RNE
    return (u16)(i >> 16);
}
// dtype-polymorphic scalar load: isbf=1 -> bf16 array, else fp32 array
__device__ inline float ldf(const void* p, long i, int isbf) {
    return isbf ? b2f(((const u16*)p)[i]) : ((const float*)p)[i];
}

// ---------------- dtype detect: q_var == ones. bf16 word0=0x3F80, fp32 word0=0x0000
__global__ void detect_kernel(const u16* __restrict__ qvar, int* __restrict__ flag) {
    if (threadIdx.x == 0) *flag = (qvar[0] == 0x3F80) ? 1 : 0;
}

// ---------------- weight transpose: W (K x N) -> Wt (N x K), bf16 out ----------
__global__ __launch_bounds__(256) void wtrans_kernel(
    const void* __restrict__ w0, const void* __restrict__ w1,
    const void* __restrict__ w2, const void* __restrict__ w3,
    u16* __restrict__ o0, u16* __restrict__ o1, u16* __restrict__ o2, u16* __restrict__ o3,
    const int* __restrict__ flag)
{
    const int isbf = *flag;
    const void* src = blockIdx.z == 0 ? w0 : blockIdx.z == 1 ? w1 : blockIdx.z == 2 ? w2 : w3;
    u16*        dst = blockIdx.z == 0 ? o0 : blockIdx.z == 1 ? o1 : blockIdx.z == 2 ? o2 : o3;
    __shared__ u16 t[32][33];
    const int tx = threadIdx.x & 31, ty = threadIdx.x >> 5;   // 32x8
    const int r0 = blockIdx.y * 32, c0 = blockIdx.x * 32;
#pragma unroll
    for (int i = 0; i < 4; i++)
        t[ty + i * 8][tx] = f2b(ldf(src, (long)(r0 + ty + i * 8) * C_ + c0 + tx, isbf));
    __syncthreads();
#pragma unroll
    for (int i = 0; i < 4; i++)
        dst[(c0 + ty + i * 8) * C_ + r0 + tx] = t[tx][ty + i * 8];
}

// ---------------- depthwise 3x3 conv + inference BN, bf16 out ------------------
__global__ __launch_bounds__(384) void dwbn_kernel(
    const void* __restrict__ x, const void* __restrict__ wdw,
    const void* __restrict__ gamma, const void* __restrict__ beta,
    const void* __restrict__ mean, const void* __restrict__ var,
    u16* __restrict__ out, int stride, int pad, int OH, int OW,
    const int* __restrict__ flag)
{
    const int isbf = *flag;
    const int c  = threadIdx.x;
    const int b  = blockIdx.x / OH;
    const int oy = blockIdx.x % OH;
    float w9[9];
#pragma unroll
    for (int i = 0; i < 9; i++) w9[i] = ldf(wdw, i * C_ + c, isbf);   // (3,3,1,C) layout
    const float al = ldf(gamma, c, isbf) * rsqrtf(ldf(var, c, isbf) + 1e-3f);
    const float bb = ldf(beta, c, isbf) - ldf(mean, c, isbf) * al;
    const int iy0 = oy * stride - pad;
    for (int ox = 0; ox < OW; ox++) {
        const int ix0 = ox * stride - pad;
        float acc = 0.f;
#pragma unroll
        for (int dy = 0; dy < 3; dy++) {
            const int yy = iy0 + dy;
            if (yy < 0 || yy >= HH) continue;
#pragma unroll
            for (int dx = 0; dx < 3; dx++) {
                const int xx = ix0 + dx;
                if (xx < 0 || xx >= WW) continue;
                acc += w9[dy * 3 + dx] * ldf(x, (long)(b * T_ + yy * WW + xx) * C_ + c, isbf);
            }
        }
        out[(long)(b * (OH * OW) + oy * OW + ox) * C_ + c] = f2b(acc * al + bb);
    }
}

// ---------------- MFMA GEMM: C(MxN) = A(MxK) @ Bt(NxK)^T, K=N=384 --------------
// MODE 0: * SCALEQ, bf16 out   MODE 1: plain, bf16 out
// MODE 3: + bias, OUTPUT DTYPE = input dtype (flag): fp32 or bf16
template <int MODE>
__global__ __launch_bounds__(256) void gemm_kernel(
    const u16* __restrict__ A, const u16* __restrict__ Bt,
    void* __restrict__ out, const void* __restrict__ bias, int M,
    const int* __restrict__ flag)
{
    __shared__ __align__(16) u16 As[128 * 32];
    __shared__ __align__(16) u16 Bs[128 * 32];
    const int tid = threadIdx.x;
    const int lane = tid & 63, wid = tid >> 6;
    const int wm = (wid & 1) * 64, wn = (wid >> 1) * 64;
    const int lm = lane & 15, lq = lane >> 4;
    const int m0 = blockIdx.x * 128, n0 = blockIdx.y * 128;

    frag_cd acc[4][4] = {};
    for (int k0 = 0; k0 < C_; k0 += 32) {
        __syncthreads();
#pragma unroll
        for (int i = 0; i < 2; i++) {
            const int q = tid + i * 256;            // 512 chunks of 8 bf16
            const int r = q >> 2, kc = (q & 3) * 8;
            int gm = m0 + r; if (gm > M - 1) gm = M - 1;
            *(uint4*)&As[r * 32 + kc] = *(const uint4*)&A[(long)gm * C_ + k0 + kc];
            *(uint4*)&Bs[r * 32 + kc] = *(const uint4*)&Bt[(long)(n0 + r) * C_ + k0 + kc];
        }
        __syncthreads();
        frag_ab af[4], bf[4];
#pragma unroll
        for (int f = 0; f < 4; f++) {
            af[f] = *(const frag_ab*)&As[(wm + f * 16 + lm) * 32 + lq * 8];
            bf[f] = *(const frag_ab*)&Bs[(wn + f * 16 + lm) * 32 + lq * 8];
        }
#pragma unroll
        for (int fm = 0; fm < 4; fm++)
#pragma unroll
            for (int fn = 0; fn < 4; fn++)
                acc[fm][fn] = __builtin_amdgcn_mfma_f32_16x16x32_bf16(af[fm], bf[fn], acc[fm][fn], 0, 0, 0);
    }

    const int isbf = (MODE == 3) ? *flag : 0;
    const float SCALEQ = 0.051031036307982884f * 1.4426950408889634f; // C^-0.5 * log2(e)
#pragma unroll
    for (int fm = 0; fm < 4; fm++) {
#pragma unroll
        for (int r = 0; r < 4; r++) {
            const int gm = m0 + wm + fm * 16 + lq * 4 + r;   // C-layout: row=(lane>>4)*4+reg
            if (gm >= M) continue;
#pragma unroll
            for (int fn = 0; fn < 4; fn++) {
                const int n = n0 + wn + fn * 16 + lm;        // col = lane&15
                float v = acc[fm][fn][r];
                if (MODE == 0) v *= SCALEQ;
                if (MODE == 3) {
                    v += ldf(bias, n, isbf);
                    if (isbf) ((u16*)out)[(long)gm * C_ + n] = f2b(v);
                    else      ((float*)out)[(long)gm * C_ + n] = v;
                } else {
                    ((u16*)out)[(long)gm * C_ + n] = f2b(v);
                }
            }
        }
    }
}

// ---------------- VALU attention (bisect round: transparent & fp32-exact) ------
// grid = B*NH*49, block 256. Each block: one (b,h), 16 query rows.
// Qp/Kp/Vp are row-major (rows x 384) bf16; head h occupies cols h*64..h*64+63.
__global__ __launch_bounds__(256) void attn_valu(
    const u16* __restrict__ Qp, const u16* __restrict__ Kp,
    const u16* __restrict__ Vp, u16* __restrict__ O)
{
    __shared__ u16 kT[64 * 177];     // kT[d*177 + j]  (transposed K slice, padded)
    __shared__ u16 vS[169 * 65];     // vS[j*65 + d]   (V slice, padded)
    __shared__ float qS[64];
    __shared__ float pbuf[256];
    __shared__ float red[256];
    __shared__ float osum[4][64];

    const int blk = blockIdx.x;
    const int iq = blk % 49;
    const int bh = blk / 49;
    const int b = bh / NH_, h = bh % NH_;
    const int tid = threadIdx.x;

    for (int e = tid; e < TK * HD; e += 256) {
        const int j = e >> 6, d = e & 63;
        const long src = ((long)(b * TK + j)) * C_ + h * HD + d;
        kT[d * 177 + j] = Kp[src];
        vS[j * 65 + d]  = Vp[src];
    }
    __syncthreads();

    for (int ii = 0; ii < 16; ii++) {
        const int i = iq * 16 + ii;
        if (tid < 64) qS[tid] = b2f(Qp[((long)(b * T_ + i)) * C_ + h * HD + tid]);
        __syncthreads();

        float s = -INFINITY;
        if (tid < TK) {
            float acc = 0.f;
#pragma unroll 8
            for (int d = 0; d < HD; d++) acc += qS[d] * b2f(kT[d * 177 + tid]);
            s = acc;    // already includes scale*log2e (folded into Qp)
        }
        pbuf[tid] = s;
        __syncthreads();
        for (int st = 128; st > 0; st >>= 1) {
            if (tid < st) pbuf[tid] = fmaxf(pbuf[tid], pbuf[tid + st]);
            __syncthreads();
        }
        const float mx = pbuf[0];
        __syncthreads();

        const float p = (tid < TK) ? exp2f(s - mx) : 0.f;
        red[tid] = p;
        __syncthreads();
        for (int st = 128; st > 0; st >>= 1) {
            if (tid < st) red[tid] += red[tid + st];
            __syncthreads();
        }
        const float linv = 1.f / red[0];
        pbuf[tid] = p;
        __syncthreads();

        const int d = tid & 63, seg = tid >> 6;
        const int j0 = seg * 43;
        const int j1 = (j0 + 43 < TK) ? j0 + 43 : TK;
        float acc = 0.f;
        for (int j = j0; j < j1; j++) acc += pbuf[j] * b2f(vS[j * 65 + d]);
        osum[seg][d] = acc;
        __syncthreads();
        if (tid < 64) {
            const float o = (osum[0][tid] + osum[1][tid] + osum[2][tid] + osum[3][tid]) * linv;
            O[((long)(b * T_ + i)) * C_ + h * HD + tid] = f2b(o);
        }
        __syncthreads();
    }
}

// ------------------------------------------------------------------------------
extern "C" void kernel_launch(void* const* d_in, const int* in_sizes, int n_in,
                              void* d_out, int out_size, void* d_ws, size_t ws_size,
                              hipStream_t stream)
{
    const void* x     = d_in[0];
    const void* wq_dw = d_in[1];
    const void* qg = d_in[2],  *qb = d_in[3];
    const void* qm = d_in[4],  *qv = d_in[5];
    const void* wk_dw = d_in[6];
    const void* kg = d_in[7],  *kb = d_in[8];
    const void* km = d_in[9],  *kvv = d_in[10];
    const void* wv_dw = d_in[11];
    const void* vg = d_in[12], *vb = d_in[13];
    const void* vm = d_in[14], *vvv = d_in[15];
    const void* Wq = d_in[16], *Wk = d_in[17];
    const void* Wv = d_in[18], *Wo = d_in[19];
    const void* bo = d_in[20];

    char* ws = (char*)d_ws;
    // attnO aliases qdw (qdw dead after the Q projection).
    u16* qdwO = (u16*)(ws + 0);            // 50176*384*2 = 38,535,168
    u16* kdw  = (u16*)(ws + 38535168);     // 10816*384*2 =  8,306,688
    u16* vdw  = (u16*)(ws + 46841856);     //                8,306,688
    u16* Qp   = (u16*)(ws + 55148544);     // 50176*384*2 = 38,535,168
    u16* Kp   = (u16*)(ws + 93683712);     // 10816*384*2 =  8,306,688
    u16* Vp   = (u16*)(ws + 101990400);    //                8,306,688
    u16* WqT  = (u16*)(ws + 110297088);    // 4 * 384*384*2 = 1,179,648
    u16* WkT  = WqT + 147456;
    u16* WvT  = WkT + 147456;
    u16* WoT  = WvT + 147456;
    int* flag = (int*)(ws + 111476736);

    detect_kernel<<<1, 64, 0, stream>>>((const u16*)qv, flag);
    wtrans_kernel<<<dim3(12, 12, 4), 256, 0, stream>>>(Wq, Wk, Wv, Wo, WqT, WkT, WvT, WoT, flag);
    dwbn_kernel<<<B_ * 28, 384, 0, stream>>>(x, wq_dw, qg, qb, qm, qv, qdwO, 1, 1, 28, 28, flag);
    dwbn_kernel<<<B_ * 13, 384, 0, stream>>>(x, wk_dw, kg, kb, km, kvv, kdw, 2, 0, 13, 13, flag);
    dwbn_kernel<<<B_ * 13, 384, 0, stream>>>(x, wv_dw, vg, vb, vm, vvv, vdw, 2, 0, 13, 13, flag);
    gemm_kernel<0><<<dim3(392, 3), 256, 0, stream>>>(qdwO, WqT, Qp, nullptr, B_ * T_, flag);
    gemm_kernel<1><<<dim3(85, 3), 256, 0, stream>>>(kdw, WkT, Kp, nullptr, B_ * TK, flag);
    gemm_kernel<1><<<dim3(85, 3), 256, 0, stream>>>(vdw, WvT, Vp, nullptr, B_ * TK, flag);
    attn_valu<<<B_ * NH_ * 49, 256, 0, stream>>>(Qp, Kp, Vp, qdwO);
    gemm_kernel<3><<<dim3(392, 3), 256, 0, stream>>>(qdwO, WoT, d_out, bo, B_ * T_, flag);
}

// Round 5
// 619.046 us; speedup vs baseline: 4.0001x; 4.0001x over previous
//
#include <hip/hip_runtime.h>
#include <hip/hip_bf16.h>
#include <math.h>
#include <cstdint>

typedef unsigned short u16;

#define B_   64
#define HH   28
#define WW   28
#define C_   384
#define NH_  6
#define HD   64
#define T_   784      // 28*28 queries
#define TK   169      // 13*13 keys
#define TKP  176      // K rows padded to 11*16
#define TKP2 192      // P/Vt k-dim padded to 6*32
#define KST  68       // LDS stride (u16) for K tile
#define VST  196      // LDS stride (u16) for Vt tile / P tile

using frag_ab = __attribute__((ext_vector_type(8))) short;   // 8 x bf16
using frag_cd = __attribute__((ext_vector_type(4))) float;   // 4 x fp32

__device__ inline float b2f(u16 u) {
    union { unsigned int i; float f; } v; v.i = ((unsigned int)u) << 16; return v.f;
}
__device__ inline u16 f2b(float f) {
    union { unsigned int i; float f; } v; v.f = f;
    unsigned int i = v.i;
    i += 0x7fffu + ((i >> 16) & 1);   // RNE
    return (u16)(i >> 16);
}
// dtype-polymorphic scalar load: isbf=1 -> bf16 array, else fp32 array
__device__ inline float ldf(const void* p, long i, int isbf) {
    return isbf ? b2f(((const u16*)p)[i]) : ((const float*)p)[i];
}

// ---------------- dtype detect: q_var == ones. bf16 word0=0x3F80, fp32 word0=0x0000
__global__ void detect_kernel(const u16* __restrict__ qvar, int* __restrict__ flag) {
    if (threadIdx.x == 0) *flag = (qvar[0] == 0x3F80) ? 1 : 0;
}

// ---------------- weight transpose: W (K x N) -> Wt (N x K), bf16 out ----------
__global__ __launch_bounds__(256) void wtrans_kernel(
    const void* __restrict__ w0, const void* __restrict__ w1,
    const void* __restrict__ w2, const void* __restrict__ w3,
    u16* __restrict__ o0, u16* __restrict__ o1, u16* __restrict__ o2, u16* __restrict__ o3,
    const int* __restrict__ flag)
{
    const int isbf = *flag;
    const void* src = blockIdx.z == 0 ? w0 : blockIdx.z == 1 ? w1 : blockIdx.z == 2 ? w2 : w3;
    u16*        dst = blockIdx.z == 0 ? o0 : blockIdx.z == 1 ? o1 : blockIdx.z == 2 ? o2 : o3;
    __shared__ u16 t[32][33];
    const int tx = threadIdx.x & 31, ty = threadIdx.x >> 5;   // 32x8
    const int r0 = blockIdx.y * 32, c0 = blockIdx.x * 32;
#pragma unroll
    for (int i = 0; i < 4; i++)
        t[ty + i * 8][tx] = f2b(ldf(src, (long)(r0 + ty + i * 8) * C_ + c0 + tx, isbf));
    __syncthreads();
#pragma unroll
    for (int i = 0; i < 4; i++)
        dst[(c0 + ty + i * 8) * C_ + r0 + tx] = t[tx][ty + i * 8];
}

// ---------------- depthwise 3x3 conv + inference BN, bf16 out ------------------
__global__ __launch_bounds__(384) void dwbn_kernel(
    const void* __restrict__ x, const void* __restrict__ wdw,
    const void* __restrict__ gamma, const void* __restrict__ beta,
    const void* __restrict__ mean, const void* __restrict__ var,
    u16* __restrict__ out, int stride, int pad, int OH, int OW,
    const int* __restrict__ flag)
{
    const int isbf = *flag;
    const int c  = threadIdx.x;
    const int b  = blockIdx.x / OH;
    const int oy = blockIdx.x % OH;
    float w9[9];
#pragma unroll
    for (int i = 0; i < 9; i++) w9[i] = ldf(wdw, i * C_ + c, isbf);   // (3,3,1,C) layout
    const float al = ldf(gamma, c, isbf) * rsqrtf(ldf(var, c, isbf) + 1e-3f);
    const float bb = ldf(beta, c, isbf) - ldf(mean, c, isbf) * al;
    const int iy0 = oy * stride - pad;
    for (int ox = 0; ox < OW; ox++) {
        const int ix0 = ox * stride - pad;
        float acc = 0.f;
#pragma unroll
        for (int dy = 0; dy < 3; dy++) {
            const int yy = iy0 + dy;
            if (yy < 0 || yy >= HH) continue;
#pragma unroll
            for (int dx = 0; dx < 3; dx++) {
                const int xx = ix0 + dx;
                if (xx < 0 || xx >= WW) continue;
                acc += w9[dy * 3 + dx] * ldf(x, (long)(b * T_ + yy * WW + xx) * C_ + c, isbf);
            }
        }
        out[(long)(b * (OH * OW) + oy * OW + ox) * C_ + c] = f2b(acc * al + bb);
    }
}

// ---------------- MFMA GEMM: C(MxN) = A(MxK) @ Bt(NxK)^T, K=N=384 --------------
// MODE 0: Q scatter to (b,h,784,64), * SCALEQ        (bf16)
// MODE 1: K/V scatter to (b,h,176,64)                (bf16)
// MODE 3: + bias, row-major, out dtype = flag (fp32/bf16)
template <int MODE>
__global__ __launch_bounds__(256) void gemm_kernel(
    const u16* __restrict__ A, const u16* __restrict__ Bt,
    void* __restrict__ out, const void* __restrict__ bias, int M,
    const int* __restrict__ flag)
{
    __shared__ __align__(16) u16 As[128 * 32];
    __shared__ __align__(16) u16 Bs[128 * 32];
    const int tid = threadIdx.x;
    const int lane = tid & 63, wid = tid >> 6;
    const int wm = (wid & 1) * 64, wn = (wid >> 1) * 64;
    const int lm = lane & 15, lq = lane >> 4;
    const int m0 = blockIdx.x * 128, n0 = blockIdx.y * 128;

    frag_cd acc[4][4] = {};
    for (int k0 = 0; k0 < C_; k0 += 32) {
        __syncthreads();
#pragma unroll
        for (int i = 0; i < 2; i++) {
            const int q = tid + i * 256;            // 512 chunks of 8 bf16
            const int r = q >> 2, kc = (q & 3) * 8;
            int gm = m0 + r; if (gm > M - 1) gm = M - 1;
            *(uint4*)&As[r * 32 + kc] = *(const uint4*)&A[(long)gm * C_ + k0 + kc];
            *(uint4*)&Bs[r * 32 + kc] = *(const uint4*)&Bt[(long)(n0 + r) * C_ + k0 + kc];
        }
        __syncthreads();
        frag_ab af[4], bf[4];
#pragma unroll
        for (int f = 0; f < 4; f++) {
            af[f] = *(const frag_ab*)&As[(wm + f * 16 + lm) * 32 + lq * 8];
            bf[f] = *(const frag_ab*)&Bs[(wn + f * 16 + lm) * 32 + lq * 8];
        }
#pragma unroll
        for (int fm = 0; fm < 4; fm++)
#pragma unroll
            for (int fn = 0; fn < 4; fn++)
                acc[fm][fn] = __builtin_amdgcn_mfma_f32_16x16x32_bf16(af[fm], bf[fn], acc[fm][fn], 0, 0, 0);
    }

    const int isbf = (MODE == 3) ? *flag : 0;
    const float SCALEQ = 0.051031036307982884f * 1.4426950408889634f; // C^-0.5 * log2(e)
#pragma unroll
    for (int fm = 0; fm < 4; fm++) {
#pragma unroll
        for (int r = 0; r < 4; r++) {
            const int gm = m0 + wm + fm * 16 + lq * 4 + r;   // C-layout: row=(lane>>4)*4+reg
            if (gm >= M) continue;
#pragma unroll
            for (int fn = 0; fn < 4; fn++) {
                const int n = n0 + wn + fn * 16 + lm;        // col = lane&15
                float v = acc[fm][fn][r];
                if (MODE == 0) {
                    const int b = gm / T_, t = gm % T_;
                    ((u16*)out)[((long)(b * NH_ + (n >> 6)) * T_ + t) * HD + (n & 63)] = f2b(v * SCALEQ);
                } else if (MODE == 1) {
                    const int b = gm / TK, j = gm % TK;
                    ((u16*)out)[((long)(b * NH_ + (n >> 6)) * TKP + j) * HD + (n & 63)] = f2b(v);
                } else {
                    v += ldf(bias, n, isbf);
                    if (isbf) ((u16*)out)[(long)gm * C_ + n] = f2b(v);
                    else      ((float*)out)[(long)gm * C_ + n] = v;
                }
            }
        }
    }
}

// ---------------- V (b,h,j,d) -> Vt (b,h,d,j) with zero pad j>=169 -------------
__global__ __launch_bounds__(256) void vtrans_kernel(const u16* __restrict__ V, u16* __restrict__ Vt)
{
    __shared__ float tile[TKP2 * 65];
    const int bh = blockIdx.x;
    for (int e = threadIdx.x; e < TKP2 * HD; e += 256) {
        const int j = e >> 6, d = e & 63;
        tile[j * 65 + d] = (j < TK) ? b2f(V[((long)bh * TKP + j) * HD + d]) : 0.f;
    }
    __syncthreads();
    for (int e = threadIdx.x; e < HD * TKP2; e += 256) {
        const int d = e / TKP2, j = e % TKP2;
        Vt[((long)bh * HD + d) * TKP2 + j] = f2b(tile[j * 65 + d]);
    }
}

// ---------------- fused attention: S=QK^T, softmax, O=PV -----------------------
// block = 4 waves, each wave owns 16 q-rows; grid = (b*h)*13 q-tiles of 64
__global__ __launch_bounds__(256) void attn_kernel(
    const u16* __restrict__ Q, const u16* __restrict__ K,
    const u16* __restrict__ Vt, u16* __restrict__ O)
{
    __shared__ __align__(16) u16 kv[64 * VST];        // phase A: K (176 x KST); phase B: Vt (64 x VST)
    __shared__ __align__(16) u16 ps[4][16 * VST];     // per-wave P, A-operand layout source
    const int qt = blockIdx.x % 13;
    const int bh = blockIdx.x / 13;
    const int b = bh / NH_, h = bh % NH_;
    const int tid = threadIdx.x, lane = tid & 63, wid = tid >> 6;
    const int lm = lane & 15, lq = lane >> 4;

    // ---- phase A: stage K tile ----
    for (int ch = tid; ch < TKP * HD / 8; ch += 256) {
        const int j = ch >> 3, dc = (ch & 7) * 8;
        *(uint4*)&kv[j * KST + dc] = *(const uint4*)&K[((long)bh * TKP + j) * HD + dc];
    }
    __syncthreads();

    const int trow = qt * 64 + wid * 16;
    int rowq = trow + lm; if (rowq > T_ - 1) rowq = T_ - 1;   // clamp; clamped rows' outputs discarded
    const frag_ab aq0 = *(const frag_ab*)&Q[((long)bh * T_ + rowq) * HD + lq * 8];
    const frag_ab aq1 = *(const frag_ab*)&Q[((long)bh * T_ + rowq) * HD + 32 + lq * 8];

    frag_cd s[11];
#pragma unroll
    for (int nt = 0; nt < 11; nt++) {
        const frag_ab bk0 = *(const frag_ab*)&kv[(nt * 16 + lm) * KST + lq * 8];
        const frag_ab bk1 = *(const frag_ab*)&kv[(nt * 16 + lm) * KST + 32 + lq * 8];
        frag_cd c = {};
        c = __builtin_amdgcn_mfma_f32_16x16x32_bf16(aq0, bk0, c, 0, 0, 0);
        c = __builtin_amdgcn_mfma_f32_16x16x32_bf16(aq1, bk1, c, 0, 0, 0);
        s[nt] = c;
    }
    // mask key columns >= 169 (tile 10 cols 160..175)
    if (lm >= 9) {
#pragma unroll
        for (int r = 0; r < 4; r++) s[10][r] = -INFINITY;
    }

    float linv[4];
#pragma unroll
    for (int r = 0; r < 4; r++) {
        float mx = -INFINITY;
#pragma unroll
        for (int nt = 0; nt < 11; nt++) mx = fmaxf(mx, s[nt][r]);
#pragma unroll
        for (int k = 1; k < 16; k <<= 1) mx = fmaxf(mx, __shfl_xor(mx, k));
        float sum = 0.f;
#pragma unroll
        for (int nt = 0; nt < 11; nt++) {
            const float p = exp2f(s[nt][r] - mx);   // scale*log2e folded into Q
            s[nt][r] = p;
            sum += p;
        }
#pragma unroll
        for (int k = 1; k < 16; k <<= 1) sum += __shfl_xor(sum, k);
        linv[r] = 1.f / sum;
    }

    // P: C-layout regs -> LDS rows (q-row major, stride VST), zero pad cols 176..191
#pragma unroll
    for (int nt = 0; nt < 11; nt++)
#pragma unroll
        for (int r = 0; r < 4; r++)
            ps[wid][(lq * 4 + r) * VST + nt * 16 + lm] = f2b(s[nt][r]);
#pragma unroll
    for (int r = 0; r < 4; r++)
        ps[wid][(lq * 4 + r) * VST + 176 + lm] = 0;
    __syncthreads();   // all waves done with K before Vt overwrites kv

    // ---- phase B: stage Vt tile (64 x 192, stride VST) ----
    for (int ch = tid; ch < HD * TKP2 / 8; ch += 256) {
        const int d = ch / 24, jc = (ch % 24) * 8;
        *(uint4*)&kv[d * VST + jc] = *(const uint4*)&Vt[((long)bh * HD + d) * TKP2 + jc];
    }
    __syncthreads();

    frag_cd o[4] = {};
#pragma unroll
    for (int kk = 0; kk < 6; kk++) {
        const frag_ab ap = *(const frag_ab*)&ps[wid][lm * VST + kk * 32 + lq * 8];
#pragma unroll
        for (int fn = 0; fn < 4; fn++) {
            const frag_ab bv = *(const frag_ab*)&kv[(fn * 16 + lm) * VST + kk * 32 + lq * 8];
            o[fn] = __builtin_amdgcn_mfma_f32_16x16x32_bf16(ap, bv, o[fn], 0, 0, 0);
        }
    }
#pragma unroll
    for (int r = 0; r < 4; r++) {
        const int t = trow + lq * 4 + r;
        if (t < T_) {
#pragma unroll
            for (int fn = 0; fn < 4; fn++)
                O[((long)(b * T_ + t)) * C_ + h * HD + fn * 16 + lm] = f2b(o[fn][r] * linv[r]);
        }
    }
}

// ------------------------------------------------------------------------------
extern "C" void kernel_launch(void* const* d_in, const int* in_sizes, int n_in,
                              void* d_out, int out_size, void* d_ws, size_t ws_size,
                              hipStream_t stream)
{
    const void* x     = d_in[0];
    const void* wq_dw = d_in[1];
    const void* qg = d_in[2],  *qb = d_in[3];
    const void* qm = d_in[4],  *qv = d_in[5];
    const void* wk_dw = d_in[6];
    const void* kg = d_in[7],  *kb = d_in[8];
    const void* km = d_in[9],  *kvv = d_in[10];
    const void* wv_dw = d_in[11];
    const void* vg = d_in[12], *vb = d_in[13];
    const void* vm = d_in[14], *vvv = d_in[15];
    const void* Wq = d_in[16], *Wk = d_in[17];
    const void* Wv = d_in[18], *Wo = d_in[19];
    const void* bo = d_in[20];

    char* ws = (char*)d_ws;
    // attn output aliases qdw (dead after Q projection); Vtb aliases kdw/vdw
    // (dead after K/V projections).
    u16* qdwO = (u16*)(ws + 0);            // 50176*384*2 = 38,535,168
    u16* kdw  = (u16*)(ws + 38535168);     // 10816*384*2 =  8,306,688
    u16* vdw  = (u16*)(ws + 46841856);     //                8,306,688
    u16* Vtb  = (u16*)(ws + 38535168);     // 2304*64*192*2 = 9,437,184 (aliases kdw+vdw)
    u16* Qb   = (u16*)(ws + 55148544);     // 2304*784*64*2 = 38,535,168
    u16* Kb   = (u16*)(ws + 93683712);     // 2304*176*64*2 =  8,650,752
    u16* Vb   = (u16*)(ws + 102334464);    //                  8,650,752
    u16* WqT  = (u16*)(ws + 110985216);    // 4 * 384*384*2 = 1,179,648
    u16* WkT  = WqT + 147456;
    u16* WvT  = WkT + 147456;
    u16* WoT  = WvT + 147456;
    int* flag = (int*)(ws + 112164864);

    detect_kernel<<<1, 64, 0, stream>>>((const u16*)qv, flag);
    wtrans_kernel<<<dim3(12, 12, 4), 256, 0, stream>>>(Wq, Wk, Wv, Wo, WqT, WkT, WvT, WoT, flag);
    dwbn_kernel<<<B_ * 28, 384, 0, stream>>>(x, wq_dw, qg, qb, qm, qv, qdwO, 1, 1, 28, 28, flag);
    dwbn_kernel<<<B_ * 13, 384, 0, stream>>>(x, wk_dw, kg, kb, km, kvv, kdw, 2, 0, 13, 13, flag);
    dwbn_kernel<<<B_ * 13, 384, 0, stream>>>(x, wv_dw, vg, vb, vm, vvv, vdw, 2, 0, 13, 13, flag);
    gemm_kernel<0><<<dim3(392, 3), 256, 0, stream>>>(qdwO, WqT, Qb, nullptr, B_ * T_, flag);
    gemm_kernel<1><<<dim3(85, 3), 256, 0, stream>>>(kdw, WkT, Kb, nullptr, B_ * TK, flag);
    gemm_kernel<1><<<dim3(85, 3), 256, 0, stream>>>(vdw, WvT, Vb, nullptr, B_ * TK, flag);
    vtrans_kernel<<<B_ * NH_, 256, 0, stream>>>(Vb, Vtb);
    attn_kernel<<<B_ * NH_ * 13, 256, 0, stream>>>(Qb, Kb, Vtb, qdwO);
    gemm_kernel<3><<<dim3(392, 3), 256, 0, stream>>>(qdwO, WoT, d_out, bo, B_ * T_, flag);
}

// Round 6
// 457.695 us; speedup vs baseline: 5.4102x; 1.3525x over previous
//
#include <hip/hip_runtime.h>
#include <hip/hip_bf16.h>
#include <math.h>
#include <cstdint>

typedef unsigned short u16;

#define B_   64
#define HH   28
#define WW   28
#define C_   384
#define NH_  6
#define HD   64
#define T_   784      // 28*28 queries
#define TK   169      // 13*13 keys
#define TKP  176      // K rows padded to 11*16
#define TKP2 192      // P/Vt k-dim padded to 6*32
#define KST  68       // LDS stride (u16) for K tile
#define VST  196      // LDS stride (u16) for Vt tile / P tile

using frag_ab = __attribute__((ext_vector_type(8))) short;   // 8 x bf16
using frag_cd = __attribute__((ext_vector_type(4))) float;   // 4 x fp32

__device__ inline float b2f(u16 u) {
    union { unsigned int i; float f; } v; v.i = ((unsigned int)u) << 16; return v.f;
}
__device__ inline u16 f2b(float f) {
    union { unsigned int i; float f; } v; v.f = f;
    unsigned int i = v.i;
    i += 0x7fffu + ((i >> 16) & 1);   // RNE
    return (u16)(i >> 16);
}
// dtype-polymorphic scalar load: isbf=1 -> bf16 array, else fp32 array
__device__ inline float ldf(const void* p, long i, int isbf) {
    return isbf ? b2f(((const u16*)p)[i]) : ((const float*)p)[i];
}
// dtype-polymorphic vector load of 4 consecutive elements (i % 4 == 0)
__device__ inline float4 ldf4(const void* p, long i, int isbf) {
    if (isbf) {
        const ushort4 u = *(const ushort4*)((const u16*)p + i);
        return make_float4(b2f(u.x), b2f(u.y), b2f(u.z), b2f(u.w));
    }
    return *(const float4*)((const float*)p + i);
}

// ---------------- dtype detect: q_var == ones. bf16 word0=0x3F80, fp32 word0=0x0000
__global__ void detect_kernel(const u16* __restrict__ qvar, int* __restrict__ flag) {
    if (threadIdx.x == 0) *flag = (qvar[0] == 0x3F80) ? 1 : 0;
}

// ---------------- weight transpose: W (K x N) -> Wt (N x K), bf16 out ----------
__global__ __launch_bounds__(256) void wtrans_kernel(
    const void* __restrict__ w0, const void* __restrict__ w1,
    const void* __restrict__ w2, const void* __restrict__ w3,
    u16* __restrict__ o0, u16* __restrict__ o1, u16* __restrict__ o2, u16* __restrict__ o3,
    const int* __restrict__ flag)
{
    const int isbf = *flag;
    const void* src = blockIdx.z == 0 ? w0 : blockIdx.z == 1 ? w1 : blockIdx.z == 2 ? w2 : w3;
    u16*        dst = blockIdx.z == 0 ? o0 : blockIdx.z == 1 ? o1 : blockIdx.z == 2 ? o2 : o3;
    __shared__ u16 t[32][33];
    const int tx = threadIdx.x & 31, ty = threadIdx.x >> 5;   // 32x8
    const int r0 = blockIdx.y * 32, c0 = blockIdx.x * 32;
#pragma unroll
    for (int i = 0; i < 4; i++)
        t[ty + i * 8][tx] = f2b(ldf(src, (long)(r0 + ty + i * 8) * C_ + c0 + tx, isbf));
    __syncthreads();
#pragma unroll
    for (int i = 0; i < 4; i++)
        dst[(c0 + ty + i * 8) * C_ + r0 + tx] = t[tx][ty + i * 8];
}

// ---------------- depthwise 3x3 conv + BN, vectorized: q path (stride 1, SAME) --
// block 384 = 4 pixels x 96 channel-quads; grid = B*784/4
__global__ __launch_bounds__(384) void dwbn_q_kernel(
    const void* __restrict__ x, const void* __restrict__ wdw,
    const void* __restrict__ gamma, const void* __restrict__ beta,
    const void* __restrict__ mean, const void* __restrict__ var,
    u16* __restrict__ out, const int* __restrict__ flag)
{
    const int isbf = *flag;
    const int tid = threadIdx.x;
    const int c = (tid % 96) * 4;
    const int pix = blockIdx.x * 4 + tid / 96;
    const int b = pix / T_, p = pix % T_;
    const int oy = p / WW, ox = p % WW;

    float4 w[9];
#pragma unroll
    for (int i = 0; i < 9; i++) w[i] = ldf4(wdw, (long)i * C_ + c, isbf);
    const float4 ga = ldf4(gamma, c, isbf), be = ldf4(beta, c, isbf);
    const float4 mn = ldf4(mean, c, isbf),  vr = ldf4(var, c, isbf);
    float4 al, bb;
    al.x = ga.x * rsqrtf(vr.x + 1e-3f); bb.x = be.x - mn.x * al.x;
    al.y = ga.y * rsqrtf(vr.y + 1e-3f); bb.y = be.y - mn.y * al.y;
    al.z = ga.z * rsqrtf(vr.z + 1e-3f); bb.z = be.z - mn.z * al.z;
    al.w = ga.w * rsqrtf(vr.w + 1e-3f); bb.w = be.w - mn.w * al.w;

    float4 acc = make_float4(0.f, 0.f, 0.f, 0.f);
    const int iy0 = oy - 1, ix0 = ox - 1;
#pragma unroll
    for (int dy = 0; dy < 3; dy++) {
        const int yy = iy0 + dy;
        if (yy < 0 || yy >= HH) continue;
#pragma unroll
        for (int dx = 0; dx < 3; dx++) {
            const int xx = ix0 + dx;
            if (xx < 0 || xx >= WW) continue;
            const float4 v = ldf4(x, ((long)(b * T_ + yy * WW + xx)) * C_ + c, isbf);
            const float4 ww = w[dy * 3 + dx];
            acc.x += ww.x * v.x; acc.y += ww.y * v.y;
            acc.z += ww.z * v.z; acc.w += ww.w * v.w;
        }
    }
    ushort4 o;
    o.x = f2b(acc.x * al.x + bb.x);
    o.y = f2b(acc.y * al.y + bb.y);
    o.z = f2b(acc.z * al.z + bb.z);
    o.w = f2b(acc.w * al.w + bb.w);
    *(ushort4*)&out[(long)pix * C_ + c] = o;
}

// ---------------- fused k+v depthwise conv + BN (stride 2, VALID, no bounds) ---
// block 384 = 4 pixels x 96 channel-quads; grid = B*169/4
__global__ __launch_bounds__(384) void dwbn_kv_kernel(
    const void* __restrict__ x,
    const void* __restrict__ wk, const void* __restrict__ kg, const void* __restrict__ kb,
    const void* __restrict__ km, const void* __restrict__ kv_,
    const void* __restrict__ wv, const void* __restrict__ vg, const void* __restrict__ vb,
    const void* __restrict__ vm, const void* __restrict__ vv,
    u16* __restrict__ outk, u16* __restrict__ outv, const int* __restrict__ flag)
{
    const int isbf = *flag;
    const int tid = threadIdx.x;
    const int c = (tid % 96) * 4;
    const int pix = blockIdx.x * 4 + tid / 96;
    const int b = pix / TK, p = pix % TK;
    const int oy = p / 13, ox = p % 13;

    float4 wwk[9], wwv[9];
#pragma unroll
    for (int i = 0; i < 9; i++) {
        wwk[i] = ldf4(wk, (long)i * C_ + c, isbf);
        wwv[i] = ldf4(wv, (long)i * C_ + c, isbf);
    }
    float4 alk, bbk, alv, bbv;
    {
        const float4 ga = ldf4(kg, c, isbf), be = ldf4(kb, c, isbf);
        const float4 mn = ldf4(km, c, isbf), vr = ldf4(kv_, c, isbf);
        alk.x = ga.x * rsqrtf(vr.x + 1e-3f); bbk.x = be.x - mn.x * alk.x;
        alk.y = ga.y * rsqrtf(vr.y + 1e-3f); bbk.y = be.y - mn.y * alk.y;
        alk.z = ga.z * rsqrtf(vr.z + 1e-3f); bbk.z = be.z - mn.z * alk.z;
        alk.w = ga.w * rsqrtf(vr.w + 1e-3f); bbk.w = be.w - mn.w * alk.w;
    }
    {
        const float4 ga = ldf4(vg, c, isbf), be = ldf4(vb, c, isbf);
        const float4 mn = ldf4(vm, c, isbf), vr = ldf4(vv, c, isbf);
        alv.x = ga.x * rsqrtf(vr.x + 1e-3f); bbv.x = be.x - mn.x * alv.x;
        alv.y = ga.y * rsqrtf(vr.y + 1e-3f); bbv.y = be.y - mn.y * alv.y;
        alv.z = ga.z * rsqrtf(vr.z + 1e-3f); bbv.z = be.z - mn.z * alv.z;
        alv.w = ga.w * rsqrtf(vr.w + 1e-3f); bbv.w = be.w - mn.w * alv.w;
    }

    float4 ak = make_float4(0.f, 0.f, 0.f, 0.f);
    float4 av = make_float4(0.f, 0.f, 0.f, 0.f);
    const int iy0 = oy * 2, ix0 = ox * 2;
#pragma unroll
    for (int dy = 0; dy < 3; dy++) {
#pragma unroll
        for (int dx = 0; dx < 3; dx++) {
            const float4 v = ldf4(x, ((long)(b * T_ + (iy0 + dy) * WW + ix0 + dx)) * C_ + c, isbf);
            const float4 k9 = wwk[dy * 3 + dx], v9 = wwv[dy * 3 + dx];
            ak.x += k9.x * v.x; ak.y += k9.y * v.y; ak.z += k9.z * v.z; ak.w += k9.w * v.w;
            av.x += v9.x * v.x; av.y += v9.y * v.y; av.z += v9.z * v.z; av.w += v9.w * v.w;
        }
    }
    ushort4 ok, ov;
    ok.x = f2b(ak.x * alk.x + bbk.x); ok.y = f2b(ak.y * alk.y + bbk.y);
    ok.z = f2b(ak.z * alk.z + bbk.z); ok.w = f2b(ak.w * alk.w + bbk.w);
    ov.x = f2b(av.x * alv.x + bbv.x); ov.y = f2b(av.y * alv.y + bbv.y);
    ov.z = f2b(av.z * alv.z + bbv.z); ov.w = f2b(av.w * alv.w + bbv.w);
    *(ushort4*)&outk[(long)pix * C_ + c] = ok;
    *(ushort4*)&outv[(long)pix * C_ + c] = ov;
}

// ---------------- MFMA GEMM: C(MxN) = A(MxK) @ Bt(NxK)^T, K=N=384 --------------
// MODE 0: Q scatter to (b,h,784,64), * SCALEQ        (bf16)
// MODE 1: K/V scatter to (b,h,176,64)                (bf16)
// MODE 3: + bias, row-major, out dtype = flag (fp32/bf16)
template <int MODE>
__global__ __launch_bounds__(256) void gemm_kernel(
    const u16* __restrict__ A, const u16* __restrict__ Bt,
    void* __restrict__ out, const void* __restrict__ bias, int M,
    const int* __restrict__ flag)
{
    __shared__ __align__(16) u16 As[128 * 32];
    __shared__ __align__(16) u16 Bs[128 * 32];
    const int tid = threadIdx.x;
    const int lane = tid & 63, wid = tid >> 6;
    const int wm = (wid & 1) * 64, wn = (wid >> 1) * 64;
    const int lm = lane & 15, lq = lane >> 4;
    const int m0 = blockIdx.x * 128, n0 = blockIdx.y * 128;

    frag_cd acc[4][4] = {};
    for (int k0 = 0; k0 < C_; k0 += 32) {
        __syncthreads();
#pragma unroll
        for (int i = 0; i < 2; i++) {
            const int q = tid + i * 256;            // 512 chunks of 8 bf16
            const int r = q >> 2, kc = (q & 3) * 8;
            int gm = m0 + r; if (gm > M - 1) gm = M - 1;
            *(uint4*)&As[r * 32 + kc] = *(const uint4*)&A[(long)gm * C_ + k0 + kc];
            *(uint4*)&Bs[r * 32 + kc] = *(const uint4*)&Bt[(long)(n0 + r) * C_ + k0 + kc];
        }
        __syncthreads();
        frag_ab af[4], bf[4];
#pragma unroll
        for (int f = 0; f < 4; f++) {
            af[f] = *(const frag_ab*)&As[(wm + f * 16 + lm) * 32 + lq * 8];
            bf[f] = *(const frag_ab*)&Bs[(wn + f * 16 + lm) * 32 + lq * 8];
        }
#pragma unroll
        for (int fm = 0; fm < 4; fm++)
#pragma unroll
            for (int fn = 0; fn < 4; fn++)
                acc[fm][fn] = __builtin_amdgcn_mfma_f32_16x16x32_bf16(af[fm], bf[fn], acc[fm][fn], 0, 0, 0);
    }

    const int isbf = (MODE == 3) ? *flag : 0;
    const float SCALEQ = 0.051031036307982884f * 1.4426950408889634f; // C^-0.5 * log2(e)
#pragma unroll
    for (int fm = 0; fm < 4; fm++) {
#pragma unroll
        for (int r = 0; r < 4; r++) {
            const int gm = m0 + wm + fm * 16 + lq * 4 + r;   // C-layout: row=(lane>>4)*4+reg
            if (gm >= M) continue;
#pragma unroll
            for (int fn = 0; fn < 4; fn++) {
                const int n = n0 + wn + fn * 16 + lm;        // col = lane&15
                float v = acc[fm][fn][r];
                if (MODE == 0) {
                    const int b = gm / T_, t = gm % T_;
                    ((u16*)out)[((long)(b * NH_ + (n >> 6)) * T_ + t) * HD + (n & 63)] = f2b(v * SCALEQ);
                } else if (MODE == 1) {
                    const int b = gm / TK, j = gm % TK;
                    ((u16*)out)[((long)(b * NH_ + (n >> 6)) * TKP + j) * HD + (n & 63)] = f2b(v);
                } else {
                    v += ldf(bias, n, isbf);
                    if (isbf) ((u16*)out)[(long)gm * C_ + n] = f2b(v);
                    else      ((float*)out)[(long)gm * C_ + n] = v;
                }
            }
        }
    }
}

// ---------------- V (b,h,j,d) -> Vt (b,h,d,j) with zero pad j>=169 -------------
__global__ __launch_bounds__(256) void vtrans_kernel(const u16* __restrict__ V, u16* __restrict__ Vt)
{
    __shared__ float tile[TKP2 * 65];
    const int bh = blockIdx.x;
    for (int e = threadIdx.x; e < TKP2 * HD; e += 256) {
        const int j = e >> 6, d = e & 63;
        tile[j * 65 + d] = (j < TK) ? b2f(V[((long)bh * TKP + j) * HD + d]) : 0.f;
    }
    __syncthreads();
    for (int e = threadIdx.x; e < HD * TKP2; e += 256) {
        const int d = e / TKP2, j = e % TKP2;
        Vt[((long)bh * HD + d) * TKP2 + j] = f2b(tile[j * 65 + d]);
    }
}

// ---------------- fused attention: S=QK^T, softmax, O=PV -----------------------
// block = 4 waves, each wave owns 16 q-rows; grid = (b*h)*13 q-tiles of 64
__global__ __launch_bounds__(256) void attn_kernel(
    const u16* __restrict__ Q, const u16* __restrict__ K,
    const u16* __restrict__ Vt, u16* __restrict__ O)
{
    __shared__ __align__(16) u16 kv[64 * VST];        // phase A: K (176 x KST); phase B: Vt (64 x VST)
    __shared__ __align__(16) u16 ps[4][16 * VST];     // per-wave P, A-operand layout source
    const int qt = blockIdx.x % 13;
    const int bh = blockIdx.x / 13;
    const int b = bh / NH_, h = bh % NH_;
    const int tid = threadIdx.x, lane = tid & 63, wid = tid >> 6;
    const int lm = lane & 15, lq = lane >> 4;

    // ---- phase A: stage K tile ----
    for (int ch = tid; ch < TKP * HD / 8; ch += 256) {
        const int j = ch >> 3, dc = (ch & 7) * 8;
        *(uint4*)&kv[j * KST + dc] = *(const uint4*)&K[((long)bh * TKP + j) * HD + dc];
    }
    __syncthreads();

    const int trow = qt * 64 + wid * 16;
    int rowq = trow + lm; if (rowq > T_ - 1) rowq = T_ - 1;   // clamp; clamped rows' outputs discarded
    const frag_ab aq0 = *(const frag_ab*)&Q[((long)bh * T_ + rowq) * HD + lq * 8];
    const frag_ab aq1 = *(const frag_ab*)&Q[((long)bh * T_ + rowq) * HD + 32 + lq * 8];

    frag_cd s[11];
#pragma unroll
    for (int nt = 0; nt < 11; nt++) {
        const frag_ab bk0 = *(const frag_ab*)&kv[(nt * 16 + lm) * KST + lq * 8];
        const frag_ab bk1 = *(const frag_ab*)&kv[(nt * 16 + lm) * KST + 32 + lq * 8];
        frag_cd c = {};
        c = __builtin_amdgcn_mfma_f32_16x16x32_bf16(aq0, bk0, c, 0, 0, 0);
        c = __builtin_amdgcn_mfma_f32_16x16x32_bf16(aq1, bk1, c, 0, 0, 0);
        s[nt] = c;
    }
    // mask key columns >= 169 (tile 10 cols 160..175)
    if (lm >= 9) {
#pragma unroll
        for (int r = 0; r < 4; r++) s[10][r] = -INFINITY;
    }

    float linv[4];
#pragma unroll
    for (int r = 0; r < 4; r++) {
        float mx = -INFINITY;
#pragma unroll
        for (int nt = 0; nt < 11; nt++) mx = fmaxf(mx, s[nt][r]);
#pragma unroll
        for (int k = 1; k < 16; k <<= 1) mx = fmaxf(mx, __shfl_xor(mx, k));
        float sum = 0.f;
#pragma unroll
        for (int nt = 0; nt < 11; nt++) {
            const float p = exp2f(s[nt][r] - mx);   // scale*log2e folded into Q
            s[nt][r] = p;
            sum += p;
        }
#pragma unroll
        for (int k = 1; k < 16; k <<= 1) sum += __shfl_xor(sum, k);
        linv[r] = 1.f / sum;
    }

    // P: C-layout regs -> LDS rows (q-row major, stride VST), zero pad cols 176..191
#pragma unroll
    for (int nt = 0; nt < 11; nt++)
#pragma unroll
        for (int r = 0; r < 4; r++)
            ps[wid][(lq * 4 + r) * VST + nt * 16 + lm] = f2b(s[nt][r]);
#pragma unroll
    for (int r = 0; r < 4; r++)
        ps[wid][(lq * 4 + r) * VST + 176 + lm] = 0;
    __syncthreads();   // all waves done with K before Vt overwrites kv

    // ---- phase B: stage Vt tile (64 x 192, stride VST) ----
    for (int ch = tid; ch < HD * TKP2 / 8; ch += 256) {
        const int d = ch / 24, jc = (ch % 24) * 8;
        *(uint4*)&kv[d * VST + jc] = *(const uint4*)&Vt[((long)bh * HD + d) * TKP2 + jc];
    }
    __syncthreads();

    frag_cd o[4] = {};
#pragma unroll
    for (int kk = 0; kk < 6; kk++) {
        const frag_ab ap = *(const frag_ab*)&ps[wid][lm * VST + kk * 32 + lq * 8];
#pragma unroll
        for (int fn = 0; fn < 4; fn++) {
            const frag_ab bv = *(const frag_ab*)&kv[(fn * 16 + lm) * VST + kk * 32 + lq * 8];
            o[fn] = __builtin_amdgcn_mfma_f32_16x16x32_bf16(ap, bv, o[fn], 0, 0, 0);
        }
    }
#pragma unroll
    for (int r = 0; r < 4; r++) {
        const int t = trow + lq * 4 + r;
        if (t < T_) {
#pragma unroll
            for (int fn = 0; fn < 4; fn++)
                O[((long)(b * T_ + t)) * C_ + h * HD + fn * 16 + lm] = f2b(o[fn][r] * linv[r]);
        }
    }
}

// ------------------------------------------------------------------------------
extern "C" void kernel_launch(void* const* d_in, const int* in_sizes, int n_in,
                              void* d_out, int out_size, void* d_ws, size_t ws_size,
                              hipStream_t stream)
{
    const void* x     = d_in[0];
    const void* wq_dw = d_in[1];
    const void* qg = d_in[2],  *qb = d_in[3];
    const void* qm = d_in[4],  *qv = d_in[5];
    const void* wk_dw = d_in[6];
    const void* kg = d_in[7],  *kb = d_in[8];
    const void* km = d_in[9],  *kvv = d_in[10];
    const void* wv_dw = d_in[11];
    const void* vg = d_in[12], *vb = d_in[13];
    const void* vm = d_in[14], *vvv = d_in[15];
    const void* Wq = d_in[16], *Wk = d_in[17];
    const void* Wv = d_in[18], *Wo = d_in[19];
    const void* bo = d_in[20];

    char* ws = (char*)d_ws;
    // attn output aliases qdw (dead after Q projection); Vtb aliases kdw/vdw
    // (dead after K/V projections).
    u16* qdwO = (u16*)(ws + 0);            // 50176*384*2 = 38,535,168
    u16* kdw  = (u16*)(ws + 38535168);     // 10816*384*2 =  8,306,688
    u16* vdw  = (u16*)(ws + 46841856);     //                8,306,688
    u16* Vtb  = (u16*)(ws + 38535168);     // 2304*64*192*2 = 9,437,184 (aliases kdw+vdw)
    u16* Qb   = (u16*)(ws + 55148544);     // 2304*784*64*2 = 38,535,168
    u16* Kb   = (u16*)(ws + 93683712);     // 2304*176*64*2 =  8,650,752
    u16* Vb   = (u16*)(ws + 102334464);    //                  8,650,752
    u16* WqT  = (u16*)(ws + 110985216);    // 4 * 384*384*2 = 1,179,648
    u16* WkT  = WqT + 147456;
    u16* WvT  = WkT + 147456;
    u16* WoT  = WvT + 147456;
    int* flag = (int*)(ws + 112164864);

    detect_kernel<<<1, 64, 0, stream>>>((const u16*)qv, flag);
    wtrans_kernel<<<dim3(12, 12, 4), 256, 0, stream>>>(Wq, Wk, Wv, Wo, WqT, WkT, WvT, WoT, flag);
    dwbn_q_kernel<<<B_ * T_ / 4, 384, 0, stream>>>(x, wq_dw, qg, qb, qm, qv, qdwO, flag);
    dwbn_kv_kernel<<<B_ * TK / 4, 384, 0, stream>>>(x, wk_dw, kg, kb, km, kvv,
                                                    wv_dw, vg, vb, vm, vvv, kdw, vdw, flag);
    gemm_kernel<0><<<dim3(392, 3), 256, 0, stream>>>(qdwO, WqT, Qb, nullptr, B_ * T_, flag);
    gemm_kernel<1><<<dim3(85, 3), 256, 0, stream>>>(kdw, WkT, Kb, nullptr, B_ * TK, flag);
    gemm_kernel<1><<<dim3(85, 3), 256, 0, stream>>>(vdw, WvT, Vb, nullptr, B_ * TK, flag);
    vtrans_kernel<<<B_ * NH_, 256, 0, stream>>>(Vb, Vtb);
    attn_kernel<<<B_ * NH_ * 13, 256, 0, stream>>>(Qb, Kb, Vtb, qdwO);
    gemm_kernel<3><<<dim3(392, 3), 256, 0, stream>>>(qdwO, WoT, d_out, bo, B_ * T_, flag);
}